// Round 10
// baseline (529.002 us; speedup 1.0000x reference)
//
#include <hip/hip_runtime.h>

typedef unsigned short ushortT;
typedef ushortT ushort8 __attribute__((ext_vector_type(8)));
typedef short bf16x8 __attribute__((ext_vector_type(8)));
typedef float f32x4 __attribute__((ext_vector_type(4)));
typedef unsigned int uint32;

#define NN 40000
#define NE 512000
#define DD 128
#define RR 8
#define NSEG (NN * RR)   // 320000
#define KT 1152          // R*D + D
#define NB_SCAN 1250     // NSEG / 256

__device__ __forceinline__ float bf2f(ushortT u) { return __uint_as_float(((unsigned)u) << 16); }
__device__ __forceinline__ ushortT f2bf(float f) {
  unsigned u = __float_as_uint(f);
  unsigned r = (u + 0x7fffu + ((u >> 16) & 1u)) >> 16;   // RNE
  return (ushortT)r;
}

// ---------------- CSR build: count / scan / fill ----------------
__global__ void count_kernel(const int* __restrict__ dst, const int* __restrict__ et,
                             int* __restrict__ cnt) {
  int e = blockIdx.x * 256 + threadIdx.x;
  if (e < NE) atomicAdd(&cnt[dst[e] * RR + et[e]], 1);
}

__global__ void scan1_kernel(const int* __restrict__ cnt, int* __restrict__ offs,
                             int* __restrict__ bsum) {
  __shared__ int s[256];
  int tid = threadIdx.x, gid = blockIdx.x * 256 + tid;
  int v = cnt[gid];            // NSEG = 1250*256 exact
  s[tid] = v; __syncthreads();
  for (int o = 1; o < 256; o <<= 1) {
    int t = (tid >= o) ? s[tid - o] : 0;
    __syncthreads(); s[tid] += t; __syncthreads();
  }
  offs[gid] = s[tid] - v;      // block-local exclusive
  if (tid == 255) bsum[blockIdx.x] = s[255];
}

__global__ void scan2_kernel(int* __restrict__ bsum) {
  __shared__ int s[256];
  __shared__ int carry, tot;
  int tid = threadIdx.x;
  if (tid == 0) carry = 0;
  __syncthreads();
  for (int base = 0; base < NB_SCAN; base += 256) {
    int i = base + tid;
    int v = (i < NB_SCAN) ? bsum[i] : 0;
    s[tid] = v; __syncthreads();
    for (int o = 1; o < 256; o <<= 1) {
      int t = (tid >= o) ? s[tid - o] : 0;
      __syncthreads(); s[tid] += t; __syncthreads();
    }
    if (i < NB_SCAN) bsum[i] = s[tid] - v + carry;
    if (tid == 255) tot = s[255];
    __syncthreads();
    if (tid == 0) carry += tot;
    __syncthreads();
  }
}

__global__ void scan3_kernel(int* __restrict__ offs, const int* __restrict__ bsum,
                             const int* __restrict__ cnt, int* __restrict__ cursor) {
  int gid = blockIdx.x * 256 + threadIdx.x;
  int v = offs[gid] + bsum[blockIdx.x];
  offs[gid] = v;
  cursor[gid] = v;
  if (gid == NSEG - 1) offs[NSEG] = v + cnt[gid];
}

__global__ void fill_kernel(const int* __restrict__ src, const int* __restrict__ dst,
                            const int* __restrict__ et, int* __restrict__ cursor,
                            int* __restrict__ srcs) {
  int e = blockIdx.x * 256 + threadIdx.x;
  if (e >= NE) return;
  int seg = dst[e] * RR + et[e];
  int slot = atomicAdd(&cursor[seg], 1);
  srcs[slot] = src[e];
}

// ---------------- h0 = prelu(num_x*lin_w + lin_b) + x  -> bf16 ----------------
__global__ void init_h_kernel(const float* __restrict__ num_x, const float* __restrict__ x,
                              const float* __restrict__ lin_w, const float* __restrict__ lin_b,
                              const float* __restrict__ a0, ushortT* __restrict__ h) {
  int idx = blockIdx.x * 256 + threadIdx.x;
  if (idx >= NN * DD) return;
  int n = idx >> 7, d = idx & 127;
  float v = fmaf(num_x[n], lin_w[d], lin_b[d]);
  v = v >= 0.f ? v : a0[d] * v;
  h[idx] = f2bf(v + x[idx]);
}

// ---------------- Wt6[layer][j][k] bf16 (transposed, K-contiguous), all 6 layers ----------------
__global__ void build_w_kernel(const float* __restrict__ bases, const float* __restrict__ comp,
                               const float* __restrict__ root, ushortT* __restrict__ Wt6) {
  int idx = blockIdx.x * 256 + threadIdx.x;  // over 6*DD*KT
  if (idx >= 6 * DD * KT) return;
  int layer = idx / (DD * KT);
  int rem = idx - layer * (DD * KT);
  int j = rem / KT, k = rem - j * KT;
  const float* B  = bases + (size_t)layer * 8 * DD * DD;
  const float* C  = comp + layer * RR * 8;
  const float* Rt = root + (size_t)layer * DD * DD;
  float s;
  if (k < RR * DD) {
    int r = k >> 7, i = k & 127;
    s = 0.f;
#pragma unroll
    for (int b = 0; b < 8; ++b) s += C[r * 8 + b] * B[(b * DD + i) * DD + j];
  } else {
    s = Rt[(k - RR * DD) * DD + j];
  }
  Wt6[idx] = f2bf(s);
}

// ---------------- aggregation v3 (R5-proven): 8 lanes/segment, 32 segments/block, 2-edge unroll ----
__global__ __launch_bounds__(256)
void agg_kernel(const int* __restrict__ offs, const int* __restrict__ srcs,
                const ushortT* __restrict__ h, ushortT* __restrict__ Xagg) {
  int seg = blockIdx.x * 32 + (threadIdx.x >> 3);   // NSEG/32 blocks exact
  int l = threadIdx.x & 7;                           // 16 cols (32 B) per lane
  int beg = offs[seg], end = offs[seg + 1];
  float a[16];
#pragma unroll
  for (int j = 0; j < 16; ++j) a[j] = 0.f;
  int e = beg;
  for (; e + 2 <= end; e += 2) {
    int s0 = srcs[e], s1 = srcs[e + 1];
    const ushortT* p0 = &h[(size_t)s0 * DD + l * 16];
    const ushortT* p1 = &h[(size_t)s1 * DD + l * 16];
    ushort8 v00 = *(const ushort8*)p0;
    ushort8 v01 = *(const ushort8*)(p0 + 8);
    ushort8 v10 = *(const ushort8*)p1;
    ushort8 v11 = *(const ushort8*)(p1 + 8);
#pragma unroll
    for (int j = 0; j < 8; ++j) {
      a[j]     += bf2f(v00[j]) + bf2f(v10[j]);
      a[8 + j] += bf2f(v01[j]) + bf2f(v11[j]);
    }
  }
  if (e < end) {
    int s0 = srcs[e];
    const ushortT* p0 = &h[(size_t)s0 * DD + l * 16];
    ushort8 v00 = *(const ushort8*)p0;
    ushort8 v01 = *(const ushort8*)(p0 + 8);
#pragma unroll
    for (int j = 0; j < 8; ++j) {
      a[j]     += bf2f(v00[j]);
      a[8 + j] += bf2f(v01[j]);
    }
  }
  float inv = (end > beg) ? 1.0f / (float)(end - beg) : 1.0f;
  ushort8 r0, r1;
#pragma unroll
  for (int j = 0; j < 8; ++j) {
    r0[j] = f2bf(a[j] * inv);
    r1[j] = f2bf(a[8 + j] * inv);
  }
  ushortT* op = &Xagg[(size_t)seg * DD + l * 16];
  *(ushort8*)op = r0;
  *(ushort8*)(op + 8) = r1;
}

// ---------------- GEMM: hout = prelu( [Xagg|h] @ Wt^T + bias ), bf16 MFMA ----------------
// BM=32 (1250 blocks), BN=128, BK=64. 4 waves: wave = 16M x 64N (acc 1x4).
// LDS 20 KB -> 8 blocks/CU (32 waves, full occupancy). Swizzled global_load_lds staging.
__global__ __launch_bounds__(256)
void gemm_kernel(const ushortT* __restrict__ Xagg, const ushortT* __restrict__ h,
                 const ushortT* __restrict__ Wt, const float* __restrict__ bias,
                 const float* __restrict__ slope, ushortT* __restrict__ hout) {
  __shared__ ushortT As[32 * 64];     // 4 KB, row pitch 128 B
  __shared__ ushortT Bs[128 * 64];    // 16 KB
  int tid = threadIdx.x, lane = tid & 63, wv = tid >> 6;
  int wr = wv >> 1, wc = wv & 1;
  int n0 = blockIdx.x * 32;
  int l8 = lane >> 3;     // 0..7: row-in-issue
  int lp = lane & 7;      // 0..7: dest 16B chunk slot
  f32x4 acc[4];
#pragma unroll
  for (int n = 0; n < 4; ++n) acc[n] = (f32x4){0.f, 0.f, 0.f, 0.f};

  for (int t = 0; t < 18; ++t) {
    int kc = t * 64;
    // ---- stage A: wave wv stages rows wv*8 .. wv*8+7 (1 issue) ----
    {
      int row = wv * 8 + l8;
      int p = lp ^ l8;                        // row&7 == l8
      const ushortT* g;
      if (kc < RR * DD) g = Xagg + (size_t)(n0 + row) * 1024 + kc + p * 8;
      else              g = h + (size_t)(n0 + row) * DD + (kc - RR * DD) + p * 8;
      __builtin_amdgcn_global_load_lds(
          (const __attribute__((address_space(1))) void*)g,
          (__attribute__((address_space(3))) void*)&As[(wv * 8) * 64], 16, 0, 0);
    }
    // ---- stage B: wave wv stages cols wv*32 .. wv*32+31, 4 issues of 8 cols ----
#pragma unroll
    for (int j = 0; j < 4; ++j) {
      int col = wv * 32 + j * 8 + l8;
      int p = lp ^ l8;                        // col&7 == l8
      const ushortT* g = Wt + (size_t)col * KT + kc + p * 8;
      __builtin_amdgcn_global_load_lds(
          (const __attribute__((address_space(1))) void*)g,
          (__attribute__((address_space(3))) void*)&Bs[(wv * 32 + j * 8) * 64], 16, 0, 0);
    }
    __syncthreads();   // compiler drains vmcnt(0) before s_barrier
#pragma unroll
    for (int kk = 0; kk < 2; ++kk) {
      int ko2 = kk * 64 + ((lane >> 4) << 4);   // byte offset of k within row
      bf16x8 a0, b[4];
      {
        int row = wr * 16 + (lane & 15);
        int off = ((row << 7) + ko2) ^ ((row & 7) << 4);
        a0 = *(const bf16x8*)((const char*)As + off);
      }
#pragma unroll
      for (int n = 0; n < 4; ++n) {
        int col = wc * 64 + n * 16 + (lane & 15);
        int off = ((col << 7) + ko2) ^ ((col & 7) << 4);
        b[n] = *(const bf16x8*)((const char*)Bs + off);
      }
#pragma unroll
      for (int n = 0; n < 4; ++n)
        acc[n] = __builtin_amdgcn_mfma_f32_16x16x32_bf16(a0, b[n], acc[n], 0, 0, 0);
    }
    __syncthreads();
  }
  // epilogue: D layout col=lane&15, row=(lane>>4)*4+reg  [m89]
  {
    int row = n0 + wr * 16 + (lane >> 4) * 4;
#pragma unroll
    for (int n = 0; n < 4; ++n) {
      int col = wc * 64 + n * 16 + (lane & 15);
      float bcol = bias[col], scol = slope[col];
#pragma unroll
      for (int q = 0; q < 4; ++q) {
        float v = acc[n][q] + bcol;
        v = v >= 0.f ? v : scol * v;
        hout[(size_t)(row + q) * DD + col] = f2bf(v);
      }
    }
  }
}

// ---------------- conv7 weight [1152][3] fp32 ----------------
__global__ void build_w7_kernel(const float* __restrict__ bases7, const float* __restrict__ comp7,
                                const float* __restrict__ root7, float* __restrict__ W7) {
  int idx = blockIdx.x * 256 + threadIdx.x;
  if (idx >= KT * 3) return;
  int row = idx / 3, c = idx - row * 3;
  if (row < RR * DD) {
    int r = row >> 7, i = row & 127;
    float s = 0.f;
#pragma unroll
    for (int b = 0; b < 8; ++b) s += comp7[r * 8 + b] * bases7[(b * DD + i) * 3 + c];
    W7[idx] = s;
  } else {
    W7[idx] = root7[(row - RR * DD) * 3 + c];
  }
}

// ---------------- conv7 + log_softmax: one wave per node, reads Xagg ----------------
__global__ void conv7_kernel(const ushortT* __restrict__ Xagg, const ushortT* __restrict__ h,
                             const float* __restrict__ W7, const float* __restrict__ bias7,
                             float* __restrict__ out) {
  int gw = (blockIdx.x * 256 + threadIdx.x) >> 6;
  if (gw >= NN) return;
  int lane = threadIdx.x & 63;
  float a0 = 0.f, a1 = 0.f, a2 = 0.f;
#pragma unroll
  for (int i = 0; i < 2; ++i) {
    int k0 = i * 512 + lane * 8;
    ushort8 v = *(const ushort8*)&Xagg[(size_t)gw * 1024 + k0];
#pragma unroll
    for (int j = 0; j < 8; ++j) {
      float xx = bf2f(v[j]);
      const float* w = &W7[(k0 + j) * 3];
      a0 = fmaf(xx, w[0], a0); a1 = fmaf(xx, w[1], a1); a2 = fmaf(xx, w[2], a2);
    }
  }
  {
    uint32 v = *(const uint32*)&h[(size_t)gw * DD + lane * 2];
    float x0 = __uint_as_float(v << 16), x1 = __uint_as_float(v & 0xffff0000u);
    int k0 = 1024 + lane * 2;
    const float* w0 = &W7[k0 * 3];
    const float* w1 = &W7[(k0 + 1) * 3];
    a0 = fmaf(x0, w0[0], a0); a1 = fmaf(x0, w0[1], a1); a2 = fmaf(x0, w0[2], a2);
    a0 = fmaf(x1, w1[0], a0); a1 = fmaf(x1, w1[1], a1); a2 = fmaf(x1, w1[2], a2);
  }
#pragma unroll
  for (int o = 32; o > 0; o >>= 1) {
    a0 += __shfl_down(a0, o);
    a1 += __shfl_down(a1, o);
    a2 += __shfl_down(a2, o);
  }
  if (lane == 0) {
    float l0 = a0 + bias7[0], l1 = a1 + bias7[1], l2 = a2 + bias7[2];
    float m = fmaxf(l0, fmaxf(l1, l2));
    float lse = m + logf(expf(l0 - m) + expf(l1 - m) + expf(l2 - m));
    out[gw * 3 + 0] = l0 - lse;
    out[gw * 3 + 1] = l1 - lse;
    out[gw * 3 + 2] = l2 - lse;
  }
}

extern "C" void kernel_launch(void* const* d_in, const int* in_sizes, int n_in,
                              void* d_out, int out_size, void* d_ws, size_t ws_size,
                              hipStream_t stream) {
  const float* num_x  = (const float*)d_in[0];
  const float* x      = (const float*)d_in[1];
  const int*   eidx   = (const int*)d_in[2];
  const int*   etype  = (const int*)d_in[3];
  const float* lin_w  = (const float*)d_in[4];
  const float* lin_b  = (const float*)d_in[5];
  const float* prelu  = (const float*)d_in[6];
  const float* bases  = (const float*)d_in[7];
  const float* comp   = (const float*)d_in[8];
  const float* root   = (const float*)d_in[9];
  const float* bias   = (const float*)d_in[10];
  const float* bases7 = (const float*)d_in[11];
  const float* comp7  = (const float*)d_in[12];
  const float* root7  = (const float*)d_in[13];
  const float* bias7  = (const float*)d_in[14];
  const int* srcv = eidx;
  const int* dstv = eidx + NE;
  float* out = (float*)d_out;

  char* p = (char*)d_ws;
  auto alloc = [&](size_t bytes) { char* q = p; p += (bytes + 255) & ~(size_t)255; return q; };
  int*     counts = (int*)alloc((size_t)NSEG * 4);
  int*     offs   = (int*)alloc((size_t)(NSEG + 1) * 4);
  int*     cursor = (int*)alloc((size_t)NSEG * 4);
  int*     bsum   = (int*)alloc((size_t)NB_SCAN * 4);
  int*     srcs   = (int*)alloc((size_t)NE * 4);
  ushortT* h0     = (ushortT*)alloc((size_t)NN * DD * 2);
  ushortT* h1     = (ushortT*)alloc((size_t)NN * DD * 2);
  ushortT* Xagg   = (ushortT*)alloc((size_t)NN * 1024 * 2);
  ushortT* Wt6    = (ushortT*)alloc((size_t)6 * DD * KT * 2);
  float*   W7     = (float*)alloc((size_t)KT * 3 * 4);
  if (ws_size < (size_t)(p - (char*)d_ws)) return;  // ~111 MB needed

  // CSR build (structure-only, once per call)
  hipMemsetAsync(counts, 0, (size_t)NSEG * 4, stream);
  count_kernel<<<NE / 256, 256, 0, stream>>>(dstv, etype, counts);
  scan1_kernel<<<NB_SCAN, 256, 0, stream>>>(counts, offs, bsum);
  scan2_kernel<<<1, 256, 0, stream>>>(bsum);
  scan3_kernel<<<NB_SCAN, 256, 0, stream>>>(offs, bsum, counts, cursor);
  fill_kernel<<<NE / 256, 256, 0, stream>>>(srcv, dstv, etype, cursor, srcs);

  init_h_kernel<<<(NN * DD + 255) / 256, 256, 0, stream>>>(num_x, x, lin_w, lin_b, prelu, h0);
  build_w_kernel<<<(6 * DD * KT + 255) / 256, 256, 0, stream>>>(bases, comp, root, Wt6);
  build_w7_kernel<<<(KT * 3 + 255) / 256, 256, 0, stream>>>(bases7, comp7, root7, W7);

  ushortT* hin = h0;
  ushortT* hout = h1;
  for (int layer = 0; layer < 6; ++layer) {
    agg_kernel<<<NSEG / 32, 256, 0, stream>>>(offs, srcs, hin, Xagg);
    gemm_kernel<<<NN / 32, 256, 0, stream>>>(Xagg, hin, Wt6 + (size_t)layer * DD * KT,
                                             bias + layer * DD, prelu + (layer + 1) * DD, hout);
    ushortT* t = hin; hin = hout; hout = t;
  }
  agg_kernel<<<NSEG / 32, 256, 0, stream>>>(offs, srcs, hin, Xagg);
  conv7_kernel<<<NN / 4, 256, 0, stream>>>(Xagg, hin, W7, bias7, out);
}

// Round 11
// 469.535 us; speedup vs baseline: 1.1267x; 1.1267x over previous
//
#include <hip/hip_runtime.h>

typedef unsigned short ushortT;
typedef ushortT ushort8 __attribute__((ext_vector_type(8)));
typedef short bf16x8 __attribute__((ext_vector_type(8)));
typedef float f32x4 __attribute__((ext_vector_type(4)));
typedef unsigned int uint32;

#define NN 40000
#define NE 512000
#define DD 128
#define RR 8
#define NSEG (NN * RR)   // 320000
#define KT 1152          // R*D + D
#define NB_SCAN 1250     // NSEG / 256
#define ECAP 320         // LDS edge cache per 32-segment block (mean ~51)

__device__ __forceinline__ float bf2f(ushortT u) { return __uint_as_float(((unsigned)u) << 16); }
__device__ __forceinline__ ushortT f2bf(float f) {
  unsigned u = __float_as_uint(f);
  unsigned r = (u + 0x7fffu + ((u >> 16) & 1u)) >> 16;   // RNE
  return (ushortT)r;
}

// ---------------- CSR build: count / scan / fill ----------------
__global__ void count_kernel(const int* __restrict__ dst, const int* __restrict__ et,
                             int* __restrict__ cnt) {
  int e = blockIdx.x * 256 + threadIdx.x;
  if (e < NE) atomicAdd(&cnt[dst[e] * RR + et[e]], 1);
}

__global__ void scan1_kernel(const int* __restrict__ cnt, int* __restrict__ offs,
                             int* __restrict__ bsum) {
  __shared__ int s[256];
  int tid = threadIdx.x, gid = blockIdx.x * 256 + tid;
  int v = cnt[gid];            // NSEG = 1250*256 exact
  s[tid] = v; __syncthreads();
  for (int o = 1; o < 256; o <<= 1) {
    int t = (tid >= o) ? s[tid - o] : 0;
    __syncthreads(); s[tid] += t; __syncthreads();
  }
  offs[gid] = s[tid] - v;      // block-local exclusive
  if (tid == 255) bsum[blockIdx.x] = s[255];
}

__global__ void scan2_kernel(int* __restrict__ bsum) {
  __shared__ int s[256];
  __shared__ int carry, tot;
  int tid = threadIdx.x;
  if (tid == 0) carry = 0;
  __syncthreads();
  for (int base = 0; base < NB_SCAN; base += 256) {
    int i = base + tid;
    int v = (i < NB_SCAN) ? bsum[i] : 0;
    s[tid] = v; __syncthreads();
    for (int o = 1; o < 256; o <<= 1) {
      int t = (tid >= o) ? s[tid - o] : 0;
      __syncthreads(); s[tid] += t; __syncthreads();
    }
    if (i < NB_SCAN) bsum[i] = s[tid] - v + carry;
    if (tid == 255) tot = s[255];
    __syncthreads();
    if (tid == 0) carry += tot;
    __syncthreads();
  }
}

__global__ void scan3_kernel(int* __restrict__ offs, const int* __restrict__ bsum,
                             const int* __restrict__ cnt, int* __restrict__ cursor) {
  int gid = blockIdx.x * 256 + threadIdx.x;
  int v = offs[gid] + bsum[blockIdx.x];
  offs[gid] = v;
  cursor[gid] = v;
  if (gid == NSEG - 1) offs[NSEG] = v + cnt[gid];
}

__global__ void fill_kernel(const int* __restrict__ src, const int* __restrict__ dst,
                            const int* __restrict__ et, int* __restrict__ cursor,
                            int* __restrict__ srcs) {
  int e = blockIdx.x * 256 + threadIdx.x;
  if (e >= NE) return;
  int seg = dst[e] * RR + et[e];
  int slot = atomicAdd(&cursor[seg], 1);
  srcs[slot] = src[e];
}

// ---------------- h0 = prelu(num_x*lin_w + lin_b) + x  -> bf16 ----------------
__global__ void init_h_kernel(const float* __restrict__ num_x, const float* __restrict__ x,
                              const float* __restrict__ lin_w, const float* __restrict__ lin_b,
                              const float* __restrict__ a0, ushortT* __restrict__ h) {
  int idx = blockIdx.x * 256 + threadIdx.x;
  if (idx >= NN * DD) return;
  int n = idx >> 7, d = idx & 127;
  float v = fmaf(num_x[n], lin_w[d], lin_b[d]);
  v = v >= 0.f ? v : a0[d] * v;
  h[idx] = f2bf(v + x[idx]);
}

// ---------------- Wt6[layer][j][k] bf16 (transposed, K-contiguous), all 6 layers ----------------
__global__ void build_w_kernel(const float* __restrict__ bases, const float* __restrict__ comp,
                               const float* __restrict__ root, ushortT* __restrict__ Wt6) {
  int idx = blockIdx.x * 256 + threadIdx.x;  // over 6*DD*KT
  if (idx >= 6 * DD * KT) return;
  int layer = idx / (DD * KT);
  int rem = idx - layer * (DD * KT);
  int j = rem / KT, k = rem - j * KT;
  const float* B  = bases + (size_t)layer * 8 * DD * DD;
  const float* C  = comp + layer * RR * 8;
  const float* Rt = root + (size_t)layer * DD * DD;
  float s;
  if (k < RR * DD) {
    int r = k >> 7, i = k & 127;
    s = 0.f;
#pragma unroll
    for (int b = 0; b < 8; ++b) s += C[r * 8 + b] * B[(b * DD + i) * DD + j];
  } else {
    s = Rt[(k - RR * DD) * DD + j];
  }
  Wt6[idx] = f2bf(s);
}

// ---------------- aggregation v5: v3 + cooperative CSR staging in LDS ----------------
// 8 lanes/segment, 32 segments/block. Block stages its 33 offs + <=320 edge IDs
// into LDS (2 coalesced passes), shortening each group's serial chain to LDS->h-gather.
__global__ __launch_bounds__(256)
void agg_kernel(const int* __restrict__ offs, const int* __restrict__ srcs,
                const ushortT* __restrict__ h, ushortT* __restrict__ Xagg) {
  __shared__ int s_offs[33];
  __shared__ int s_srcs[ECAP];
  int tid = threadIdx.x;
  int sb = blockIdx.x * 32;                 // NSEG/32 blocks exact
  if (tid < 33) s_offs[tid] = offs[sb + tid];
  __syncthreads();
  int e_base = s_offs[0];
  int nE = s_offs[32] - e_base;
  for (int i = tid; i < nE && i < ECAP; i += 256) s_srcs[i] = srcs[e_base + i];
  __syncthreads();

  int g = tid >> 3;                          // segment group 0..31
  int l = tid & 7;                           // 16 cols (32 B) per lane
  int beg = s_offs[g], end = s_offs[g + 1];
  float a[16];
#pragma unroll
  for (int j = 0; j < 16; ++j) a[j] = 0.f;
  int e = beg;
  for (; e + 2 <= end; e += 2) {
    int i0 = e - e_base, i1 = i0 + 1;
    int s0 = (i0 < ECAP) ? s_srcs[i0] : srcs[e];
    int s1 = (i1 < ECAP) ? s_srcs[i1] : srcs[e + 1];
    const ushortT* p0 = &h[(size_t)s0 * DD + l * 16];
    const ushortT* p1 = &h[(size_t)s1 * DD + l * 16];
    ushort8 v00 = *(const ushort8*)p0;
    ushort8 v01 = *(const ushort8*)(p0 + 8);
    ushort8 v10 = *(const ushort8*)p1;
    ushort8 v11 = *(const ushort8*)(p1 + 8);
#pragma unroll
    for (int j = 0; j < 8; ++j) {
      a[j]     += bf2f(v00[j]) + bf2f(v10[j]);
      a[8 + j] += bf2f(v01[j]) + bf2f(v11[j]);
    }
  }
  if (e < end) {
    int i0 = e - e_base;
    int s0 = (i0 < ECAP) ? s_srcs[i0] : srcs[e];
    const ushortT* p0 = &h[(size_t)s0 * DD + l * 16];
    ushort8 v00 = *(const ushort8*)p0;
    ushort8 v01 = *(const ushort8*)(p0 + 8);
#pragma unroll
    for (int j = 0; j < 8; ++j) {
      a[j]     += bf2f(v00[j]);
      a[8 + j] += bf2f(v01[j]);
    }
  }
  float inv = (end > beg) ? 1.0f / (float)(end - beg) : 1.0f;
  ushort8 r0, r1;
#pragma unroll
  for (int j = 0; j < 8; ++j) {
    r0[j] = f2bf(a[j] * inv);
    r1[j] = f2bf(a[8 + j] * inv);
  }
  ushortT* op = &Xagg[(size_t)(sb + g) * DD + l * 16];
  *(ushort8*)op = r0;
  *(ushort8*)(op + 8) = r1;
}

// ---------------- GEMM: hout = prelu( [Xagg|h] @ Wt^T + bias ), bf16 MFMA ----------------
// BM=64 (625 blocks exact), BN=128, BK=64. 4 waves: wave = 32M x 64N.
// 2-phase pipeline: STAGE(buf^1, t+1) issued before computing buf[t].
__global__ __launch_bounds__(256)
void gemm_kernel(const ushortT* __restrict__ Xagg, const ushortT* __restrict__ h,
                 const ushortT* __restrict__ Wt, const float* __restrict__ bias,
                 const float* __restrict__ slope, ushortT* __restrict__ hout) {
  __shared__ ushortT As[2][64 * 64];     // 2 x 8 KB
  __shared__ ushortT Bs[2][128 * 64];    // 2 x 16 KB
  int tid = threadIdx.x, lane = tid & 63, wv = tid >> 6;
  int wr = wv >> 1, wc = wv & 1;
  int n0 = blockIdx.x * 64;
  int l8 = lane >> 3;     // 0..7: row-in-issue
  int lp = lane & 7;      // 0..7: dest 16B chunk slot
  f32x4 acc[2][4];
#pragma unroll
  for (int m = 0; m < 2; ++m)
#pragma unroll
    for (int n = 0; n < 4; ++n) acc[m][n] = (f32x4){0.f, 0.f, 0.f, 0.f};

  auto stage = [&](int buf, int t) {
    int kc = t * 64;
    // A: wave wv stages rows wv*16 .. wv*16+15, 2 issues of 8 rows
#pragma unroll
    for (int j = 0; j < 2; ++j) {
      int row = wv * 16 + j * 8 + l8;
      int p = lp ^ (row & 7);                 // pre-swizzled source chunk
      const ushortT* g;
      if (kc < RR * DD) g = Xagg + (size_t)(n0 + row) * 1024 + kc + p * 8;
      else              g = h + (size_t)(n0 + row) * DD + (kc - RR * DD) + p * 8;
      __builtin_amdgcn_global_load_lds(
          (const __attribute__((address_space(1))) void*)g,
          (__attribute__((address_space(3))) void*)&As[buf][(wv * 16 + j * 8) * 64], 16, 0, 0);
    }
    // B: wave wv stages cols wv*32 .. wv*32+31, 4 issues of 8 cols
#pragma unroll
    for (int j = 0; j < 4; ++j) {
      int col = wv * 32 + j * 8 + l8;
      int p = lp ^ (col & 7);
      const ushortT* g = Wt + (size_t)col * KT + kc + p * 8;
      __builtin_amdgcn_global_load_lds(
          (const __attribute__((address_space(1))) void*)g,
          (__attribute__((address_space(3))) void*)&Bs[buf][(wv * 32 + j * 8) * 64], 16, 0, 0);
    }
  };

  stage(0, 0);
  __syncthreads();
  for (int t = 0; t < 18; ++t) {
    int cur = t & 1;
    if (t + 1 < 18) stage(cur ^ 1, t + 1);
#pragma unroll
    for (int kk = 0; kk < 2; ++kk) {
      int ko2 = kk * 64 + (lane >> 4) * 16;   // byte offset of k within row
      bf16x8 a[2], b[4];
#pragma unroll
      for (int m = 0; m < 2; ++m) {
        int row = wr * 32 + m * 16 + (lane & 15);
        int off = ((row << 7) + ko2) ^ ((row & 7) << 4);
        a[m] = *(const bf16x8*)((const char*)As[cur] + off);
      }
#pragma unroll
      for (int n = 0; n < 4; ++n) {
        int col = wc * 64 + n * 16 + (lane & 15);
        int off = ((col << 7) + ko2) ^ ((col & 7) << 4);
        b[n] = *(const bf16x8*)((const char*)Bs[cur] + off);
      }
#pragma unroll
      for (int m = 0; m < 2; ++m)
#pragma unroll
        for (int n = 0; n < 4; ++n)
          acc[m][n] = __builtin_amdgcn_mfma_f32_16x16x32_bf16(a[m], b[n], acc[m][n], 0, 0, 0);
    }
    __syncthreads();   // drains next-tile DMA (vmcnt 0) + guards buf reuse
  }
  // epilogue: D layout col=lane&15, row=(lane>>4)*4+reg  [m89]
#pragma unroll
  for (int m = 0; m < 2; ++m) {
    int row = n0 + wr * 32 + m * 16 + (lane >> 4) * 4;
#pragma unroll
    for (int n = 0; n < 4; ++n) {
      int col = wc * 64 + n * 16 + (lane & 15);
      float bcol = bias[col], scol = slope[col];
#pragma unroll
      for (int q = 0; q < 4; ++q) {
        float v = acc[m][n][q] + bcol;
        v = v >= 0.f ? v : scol * v;
        hout[(size_t)(row + q) * DD + col] = f2bf(v);
      }
    }
  }
}

// ---------------- conv7 weight [1152][3] fp32 ----------------
__global__ void build_w7_kernel(const float* __restrict__ bases7, const float* __restrict__ comp7,
                                const float* __restrict__ root7, float* __restrict__ W7) {
  int idx = blockIdx.x * 256 + threadIdx.x;
  if (idx >= KT * 3) return;
  int row = idx / 3, c = idx - row * 3;
  if (row < RR * DD) {
    int r = row >> 7, i = row & 127;
    float s = 0.f;
#pragma unroll
    for (int b = 0; b < 8; ++b) s += comp7[r * 8 + b] * bases7[(b * DD + i) * 3 + c];
    W7[idx] = s;
  } else {
    W7[idx] = root7[(row - RR * DD) * 3 + c];
  }
}

// ---------------- conv7 + log_softmax: one wave per node, reads Xagg ----------------
__global__ void conv7_kernel(const ushortT* __restrict__ Xagg, const ushortT* __restrict__ h,
                             const float* __restrict__ W7, const float* __restrict__ bias7,
                             float* __restrict__ out) {
  int gw = (blockIdx.x * 256 + threadIdx.x) >> 6;
  if (gw >= NN) return;
  int lane = threadIdx.x & 63;
  float a0 = 0.f, a1 = 0.f, a2 = 0.f;
#pragma unroll
  for (int i = 0; i < 2; ++i) {
    int k0 = i * 512 + lane * 8;
    ushort8 v = *(const ushort8*)&Xagg[(size_t)gw * 1024 + k0];
#pragma unroll
    for (int j = 0; j < 8; ++j) {
      float xx = bf2f(v[j]);
      const float* w = &W7[(k0 + j) * 3];
      a0 = fmaf(xx, w[0], a0); a1 = fmaf(xx, w[1], a1); a2 = fmaf(xx, w[2], a2);
    }
  }
  {
    uint32 v = *(const uint32*)&h[(size_t)gw * DD + lane * 2];
    float x0 = __uint_as_float(v << 16), x1 = __uint_as_float(v & 0xffff0000u);
    int k0 = 1024 + lane * 2;
    const float* w0 = &W7[k0 * 3];
    const float* w1 = &W7[(k0 + 1) * 3];
    a0 = fmaf(x0, w0[0], a0); a1 = fmaf(x0, w0[1], a1); a2 = fmaf(x0, w0[2], a2);
    a0 = fmaf(x1, w1[0], a0); a1 = fmaf(x1, w1[1], a1); a2 = fmaf(x1, w1[2], a2);
  }
#pragma unroll
  for (int o = 32; o > 0; o >>= 1) {
    a0 += __shfl_down(a0, o);
    a1 += __shfl_down(a1, o);
    a2 += __shfl_down(a2, o);
  }
  if (lane == 0) {
    float l0 = a0 + bias7[0], l1 = a1 + bias7[1], l2 = a2 + bias7[2];
    float m = fmaxf(l0, fmaxf(l1, l2));
    float lse = m + logf(expf(l0 - m) + expf(l1 - m) + expf(l2 - m));
    out[gw * 3 + 0] = l0 - lse;
    out[gw * 3 + 1] = l1 - lse;
    out[gw * 3 + 2] = l2 - lse;
  }
}

extern "C" void kernel_launch(void* const* d_in, const int* in_sizes, int n_in,
                              void* d_out, int out_size, void* d_ws, size_t ws_size,
                              hipStream_t stream) {
  const float* num_x  = (const float*)d_in[0];
  const float* x      = (const float*)d_in[1];
  const int*   eidx   = (const int*)d_in[2];
  const int*   etype  = (const int*)d_in[3];
  const float* lin_w  = (const float*)d_in[4];
  const float* lin_b  = (const float*)d_in[5];
  const float* prelu  = (const float*)d_in[6];
  const float* bases  = (const float*)d_in[7];
  const float* comp   = (const float*)d_in[8];
  const float* root   = (const float*)d_in[9];
  const float* bias   = (const float*)d_in[10];
  const float* bases7 = (const float*)d_in[11];
  const float* comp7  = (const float*)d_in[12];
  const float* root7  = (const float*)d_in[13];
  const float* bias7  = (const float*)d_in[14];
  const int* srcv = eidx;
  const int* dstv = eidx + NE;
  float* out = (float*)d_out;

  char* p = (char*)d_ws;
  auto alloc = [&](size_t bytes) { char* q = p; p += (bytes + 255) & ~(size_t)255; return q; };
  int*     counts = (int*)alloc((size_t)NSEG * 4);
  int*     offs   = (int*)alloc((size_t)(NSEG + 1) * 4);
  int*     cursor = (int*)alloc((size_t)NSEG * 4);
  int*     bsum   = (int*)alloc((size_t)NB_SCAN * 4);
  int*     srcs   = (int*)alloc((size_t)NE * 4);
  ushortT* h0     = (ushortT*)alloc((size_t)NN * DD * 2);
  ushortT* h1     = (ushortT*)alloc((size_t)NN * DD * 2);
  ushortT* Xagg   = (ushortT*)alloc((size_t)NN * 1024 * 2);
  ushortT* Wt6    = (ushortT*)alloc((size_t)6 * DD * KT * 2);
  float*   W7     = (float*)alloc((size_t)KT * 3 * 4);
  if (ws_size < (size_t)(p - (char*)d_ws)) return;  // ~111 MB needed

  // CSR build (structure-only, once per call)
  hipMemsetAsync(counts, 0, (size_t)NSEG * 4, stream);
  count_kernel<<<NE / 256, 256, 0, stream>>>(dstv, etype, counts);
  scan1_kernel<<<NB_SCAN, 256, 0, stream>>>(counts, offs, bsum);
  scan2_kernel<<<1, 256, 0, stream>>>(bsum);
  scan3_kernel<<<NB_SCAN, 256, 0, stream>>>(offs, bsum, counts, cursor);
  fill_kernel<<<NE / 256, 256, 0, stream>>>(srcv, dstv, etype, cursor, srcs);

  init_h_kernel<<<(NN * DD + 255) / 256, 256, 0, stream>>>(num_x, x, lin_w, lin_b, prelu, h0);
  build_w_kernel<<<(6 * DD * KT + 255) / 256, 256, 0, stream>>>(bases, comp, root, Wt6);
  build_w7_kernel<<<(KT * 3 + 255) / 256, 256, 0, stream>>>(bases7, comp7, root7, W7);

  ushortT* hin = h0;
  ushortT* hout = h1;
  for (int layer = 0; layer < 6; ++layer) {
    agg_kernel<<<NSEG / 32, 256, 0, stream>>>(offs, srcs, hin, Xagg);
    gemm_kernel<<<NN / 64, 256, 0, stream>>>(Xagg, hin, Wt6 + (size_t)layer * DD * KT,
                                             bias + layer * DD, prelu + (layer + 1) * DD, hout);
    ushortT* t = hin; hin = hout; hout = t;
  }
  agg_kernel<<<NSEG / 32, 256, 0, stream>>>(offs, srcs, hin, Xagg);
  conv7_kernel<<<NN / 4, 256, 0, stream>>>(Xagg, hin, W7, bias7, out);
}